// Round 7
// baseline (271.977 us; speedup 1.0000x reference)
//
#include <hip/hip_runtime.h>

typedef __attribute__((ext_vector_type(8))) short s16x8;
typedef __attribute__((ext_vector_type(4))) short s16x4;
typedef __attribute__((ext_vector_type(4))) float fx4;

__device__ inline unsigned short f2bf(float f) {
  unsigned u = __float_as_uint(f);
  u += 0x7fffu + ((u >> 16) & 1u);
  return (unsigned short)(u >> 16);
}
__device__ inline float bf2f(unsigned short s) {
  return __uint_as_float(((unsigned)s) << 16);
}

#define GLDS16(gp, lp) \
  __builtin_amdgcn_global_load_lds((const __attribute__((address_space(1))) void*)(gp), \
                                   (__attribute__((address_space(3))) void*)(lp), 16, 0, 0)

// ---------------- cast_x: x f32 -> xb bf16 [b][n][c], xT bf16 [b][c][n],
// s_part[b][nt][c] = per-64-row column sums. grid 4096 = b*512 + nt*8 + ct.
__global__ __launch_bounds__(256) void cast_x_k(const float* __restrict__ x,
                                                unsigned short* __restrict__ xb,
                                                unsigned short* __restrict__ xT,
                                                float* __restrict__ s_part) {
  __shared__ unsigned short lt[64 * 66];  // [c][n] transposed tile
  __shared__ float red[64 * 4];
  int blk = blockIdx.x;
  int b = blk >> 9, r = blk & 511, nt = r >> 3, ct = r & 7;
  int n0 = nt * 64, c0 = ct * 64;
  int t = threadIdx.x;
  int rn = t >> 2, seg = (t & 3) * 16;
  const float* xp = x + ((size_t)b * 4096 + n0 + rn) * 512 + c0 + seg;
  fx4 v0 = *(const fx4*)&xp[0], v1 = *(const fx4*)&xp[4];
  fx4 v2 = *(const fx4*)&xp[8], v3 = *(const fx4*)&xp[12];
  unsigned short h[16];
  h[0]=f2bf(v0[0]); h[1]=f2bf(v0[1]); h[2]=f2bf(v0[2]); h[3]=f2bf(v0[3]);
  h[4]=f2bf(v1[0]); h[5]=f2bf(v1[1]); h[6]=f2bf(v1[2]); h[7]=f2bf(v1[3]);
  h[8]=f2bf(v2[0]); h[9]=f2bf(v2[1]); h[10]=f2bf(v2[2]); h[11]=f2bf(v2[3]);
  h[12]=f2bf(v3[0]); h[13]=f2bf(v3[1]); h[14]=f2bf(v3[2]); h[15]=f2bf(v3[3]);
  unsigned short* xbo = xb + ((size_t)b * 4096 + n0 + rn) * 512 + c0 + seg;
  *(s16x8*)&xbo[0] = *(s16x8*)&h[0];
  *(s16x8*)&xbo[8] = *(s16x8*)&h[8];
#pragma unroll
  for (int k = 0; k < 16; ++k) lt[(seg + k) * 66 + rn] = h[k];
  __syncthreads();
  // column sums (over n) of this 64x64 tile
  {
    int c = t & 63, q = t >> 6;
    float p = 0.f;
#pragma unroll
    for (int i = 0; i < 16; ++i) p += bf2f(lt[c * 66 + q * 16 + i]);
    red[c * 4 + q] = p;
  }
  __syncthreads();
  if (t < 64) {
    float s = red[t * 4] + red[t * 4 + 1] + red[t * 4 + 2] + red[t * 4 + 3];
    s_part[((size_t)(b * 64 + nt)) * 512 + c0 + t] = s;
  }
  // transposed write
  int c = t >> 2, nseg = (t & 3) * 16;
  unsigned short* xto = xT + ((size_t)b * 512 + c0 + c) * 4096 + n0 + nseg;
  *(s16x8*)&xto[0] = *(s16x8*)&lt[c * 66 + nseg];
  *(s16x8*)&xto[8] = *(s16x8*)&lt[c * 66 + nseg + 8];
}

// ---------------- wkT[e][c] = bf16(w_qkv[c][512+e]).  grid 64 = rt*8+ct (64x64 tiles)
__global__ __launch_bounds__(256) void wk_t_k(const float* __restrict__ w,
                                              unsigned short* __restrict__ wkT) {
  __shared__ unsigned short lt[64 * 66];  // [j][c]
  int blk = blockIdx.x;
  int rt = blk >> 3, ct = blk & 7;  // rt: e-tile, ct: c-tile
  int t = threadIdx.x;
  int rn = t >> 2, seg = (t & 3) * 16;  // rn: c-row, seg: j-cols
  const float* wp = w + (size_t)(ct * 64 + rn) * 1536 + 512 + rt * 64 + seg;
#pragma unroll
  for (int k = 0; k < 16; ++k) lt[(seg + k) * 66 + rn] = f2bf(wp[k]);
  __syncthreads();
  int j = t >> 2, nseg = (t & 3) * 16;
  unsigned short* o = wkT + (size_t)(rt * 64 + j) * 512 + ct * 64 + nseg;
  *(s16x8*)&o[0] = *(s16x8*)&lt[j * 66 + nseg];
  *(s16x8*)&o[8] = *(s16x8*)&lt[j * 66 + nseg + 8];
}

// ---------------- wvb[c][e] = bf16(w_qkv[c][1024+e]); wpb = bf16(w_p). grid 256.
__global__ __launch_bounds__(256) void wvwp_k(const float* __restrict__ w,
                                              const float* __restrict__ wp,
                                              unsigned short* __restrict__ wvb,
                                              unsigned short* __restrict__ wpb) {
  int blk = blockIdx.x, t = threadIdx.x;
  if (blk < 128) {
    int o = blk * 2048 + t * 8;
    int c = o >> 9, e = o & 511;
    const float* src = w + (size_t)c * 1536 + 1024 + e;
    unsigned short h[8];
#pragma unroll
    for (int i = 0; i < 8; ++i) h[i] = f2bf(src[i]);
    *(s16x8*)&wvb[o] = *(s16x8*)&h[0];
  } else {
    int o = (blk - 128) * 2048 + t * 8;
    unsigned short h[8];
#pragma unroll
    for (int i = 0; i < 8; ++i) h[i] = f2bf(wp[o + i]);
    *(s16x8*)&wpb[o] = *(s16x8*)&h[0];
  }
}

// ---------------- ub: u[b][j] = dot(s_b, w_qkv[:, j]) for j<1024; init bias_out=b_p.
// grid 32 = b*4 + cq (c-quarter of 128)
__global__ __launch_bounds__(256) void ub_k(const float* __restrict__ s_part,
                                            const float* __restrict__ w,
                                            const float* __restrict__ b_p,
                                            float* __restrict__ u,
                                            float* __restrict__ bias_out) {
  __shared__ float sb[128];
  int b = blockIdx.x >> 2, cq = blockIdx.x & 3;
  int t = threadIdx.x;
  if (t < 128) {
    float a = 0.f;
    for (int nt = 0; nt < 64; ++nt)
      a += s_part[((size_t)(b * 64 + nt)) * 512 + cq * 128 + t];
    sb[t] = a;
  }
  __syncthreads();
  float ua0 = 0.f, ua1 = 0.f, ua2 = 0.f, ua3 = 0.f;
  for (int c = 0; c < 128; ++c) {
    float sc = sb[c];
    const float* wr = w + (size_t)(cq * 128 + c) * 1536;
    ua0 += sc * wr[t];
    ua1 += sc * wr[t + 256];
    ua2 += sc * wr[t + 512];
    ua3 += sc * wr[t + 768];
  }
  atomicAdd(&u[b * 1024 + t], ua0);
  atomicAdd(&u[b * 1024 + t + 256], ua1);
  atomicAdd(&u[b * 1024 + t + 512], ua2);
  atomicAdd(&u[b * 1024 + t + 768], ua3);
  if (cq == 0) {
    bias_out[b * 512 + t] = b_p[t];
    bias_out[b * 512 + 256 + t] = b_p[256 + t];
  }
}

// ---------------- GEMM: 128x128 tile, BK=32, 4 waves, 2-phase dbuf (R6-verified).
// MODE 0 (kT):    A=wkT[512][512], BT=xb_b[4096][512], bias/row -> kT[b][e][4096] bf16
// MODE 1 (P):     A=xT_b[512][4096]+ks*1024, BT=kT_b likewise, K=1024 -> Ppart f32
// MODE 2 (Wcomb): A=weffT_b[512][512], BT=wvb[512][512] -> wcombT[b][j][c] bf16
// MODE 3 (final): A=xb_b[4096][512], BT=wcombT_b, bias/col -> out f32
template <int MODE>
__global__ __launch_bounds__(256, 4) void gemm_k(
    const unsigned short* __restrict__ A0, const unsigned short* __restrict__ B0,
    const float* __restrict__ bias, unsigned short* __restrict__ obf,
    float* __restrict__ of32) {
  constexpr int LD = (MODE == 1) ? 4096 : 512;
  constexpr int KSTEPS = (MODE == 1) ? 32 : 16;
  constexpr int NWG = (MODE == 0) ? 1024 : (MODE == 1) ? 512 : (MODE == 2) ? 128 : 1024;
  __shared__ alignas(16) unsigned short As[2][128 * 32];
  __shared__ alignas(16) unsigned short Bs[2][128 * 32];
  int tid = threadIdx.x, wave = tid >> 6, lane = tid & 63;
  int l15 = lane & 15, l16 = lane >> 4;
  int wr = wave >> 1, wc = wave & 1;

  int bid = (blockIdx.x & 7) * (NWG >> 3) + (blockIdx.x >> 3);
  int b = 0, mt = 0, nt = 0, ks = 0;
  if (MODE == 0) { b = bid >> 7; int r = bid & 127; mt = r >> 5; nt = r & 31; }
  else if (MODE == 1) { ks = bid >> 7; int r = bid & 127; b = r >> 4; mt = (r >> 2) & 3; nt = r & 3; }
  else if (MODE == 2) { b = bid >> 4; mt = (bid >> 2) & 3; nt = bid & 3; }
  else { b = bid >> 7; int r = bid & 127; mt = r >> 2; nt = r & 3; }

  const unsigned short* Ab;
  const unsigned short* Bb;
  if (MODE == 0) { Ab = A0 + (size_t)mt * 128 * 512; Bb = B0 + ((size_t)b * 4096 + nt * 128) * 512; }
  else if (MODE == 1) { Ab = A0 + ((size_t)b * 512 + mt * 128) * 4096 + ks * 1024;
                        Bb = B0 + ((size_t)b * 512 + nt * 128) * 4096 + ks * 1024; }
  else if (MODE == 2) { Ab = A0 + ((size_t)b * 512 + mt * 128) * 512; Bb = B0 + (size_t)nt * 128 * 512; }
  else { Ab = A0 + ((size_t)b * 4096 + mt * 128) * 512; Bb = B0 + ((size_t)b * 512 + nt * 128) * 512; }

  fx4 acc[4][4];
#pragma unroll
  for (int i = 0; i < 4; ++i)
#pragma unroll
    for (int j = 0; j < 4; ++j) acc[i][j] = (fx4){0.f, 0.f, 0.f, 0.f};

  int smr = wave * 16 + (lane >> 2);
  int skk = (((lane & 3) ^ ((lane >> 3) & 3))) * 8;
  const unsigned short* agp = Ab + (size_t)smr * LD + skk;
  const unsigned short* bgp = Bb + (size_t)smr * LD + skk;
  int ldsoff = wave * 512;

#define STAGE(buf, kt_)                                          \
  do {                                                           \
    int k0_ = (kt_) * 32;                                        \
    GLDS16(agp + k0_, &As[buf][ldsoff]);                         \
    GLDS16(agp + (size_t)64 * LD + k0_, &As[buf][ldsoff + 2048]);\
    GLDS16(bgp + k0_, &Bs[buf][ldsoff]);                         \
    GLDS16(bgp + (size_t)64 * LD + k0_, &Bs[buf][ldsoff + 2048]);\
  } while (0)

  STAGE(0, 0);
  asm volatile("s_waitcnt vmcnt(0)" ::: "memory");
  __builtin_amdgcn_s_barrier();

  int g = (l15 >> 1) & 3;
  int pa = (l16 ^ g) << 3;

  for (int kt = 0; kt < KSTEPS; ++kt) {
    int cur = kt & 1;
    if (kt < KSTEPS - 1) STAGE(cur ^ 1, kt + 1);

    s16x8 af[4], bf[4];
#pragma unroll
    for (int mi = 0; mi < 4; ++mi)
      af[mi] = *(const s16x8*)&As[cur][(wr * 64 + mi * 16 + l15) * 32 + pa];
#pragma unroll
    for (int nj = 0; nj < 4; ++nj)
      bf[nj] = *(const s16x8*)&Bs[cur][(wc * 64 + nj * 16 + l15) * 32 + pa];
#pragma unroll
    for (int mi = 0; mi < 4; ++mi)
#pragma unroll
      for (int nj = 0; nj < 4; ++nj)
        acc[mi][nj] = __builtin_amdgcn_mfma_f32_16x16x32_bf16(af[mi], bf[nj], acc[mi][nj], 0, 0, 0);

    asm volatile("s_waitcnt vmcnt(0)" ::: "memory");
    __builtin_amdgcn_s_barrier();
  }
#undef STAGE

  int R0 = mt * 128 + wr * 64, C0 = nt * 128 + wc * 64;
#pragma unroll
  for (int mi = 0; mi < 4; ++mi)
#pragma unroll
    for (int nj = 0; nj < 4; ++nj) {
      int gc = C0 + nj * 16 + l15;
#pragma unroll
      for (int r = 0; r < 4; ++r) {
        int gr = R0 + mi * 16 + l16 * 4 + r;
        float val = acc[mi][nj][r];
        if (MODE == 0) {
          obf[((size_t)(b * 512 + gr)) * 4096 + gc] = f2bf(val + bias[gr]);
        } else if (MODE == 1) {
          of32[((size_t)((ks * 8 + b) * 512 + gr)) * 512 + gc] = val;
        } else if (MODE == 2) {
          obf[((size_t)(b * 512 + gr)) * 512 + gc] = f2bf(val);
        } else {
          of32[((size_t)(b * 4096 + gr)) * 512 + gc] = val + bias[b * 512 + gc];
        }
      }
    }
}

// ---------------- scores + softmax + Weff (+bias_out partials). grid 64 = (b,h).
// S[d,e] = sum_c Wq[c,hd] * P_b[c,he] + bq[hd]*ksum[he]; *temp; softmax rows d;
// Weff[he,j] = sum_d attn[d,e]*wp[hd,j] -> weffT[b][j][he] bf16.
__global__ __launch_bounds__(256) void scores_k(
    const float* __restrict__ Ppart, const float* __restrict__ w_qkv,
    const float* __restrict__ b_qkv, const float* __restrict__ u,
    const float* __restrict__ temp, const unsigned short* __restrict__ wpb,
    unsigned short* __restrict__ weffT, float* __restrict__ bias_out) {
  __shared__ alignas(16) float Ps[64 * 64];
  __shared__ alignas(16) float Ws[64 * 64];
  __shared__ alignas(16) float Ss[64 * 64];
  __shared__ alignas(16) unsigned short wps[64 * 128];
  int bh = blockIdx.x;
  int b = bh >> 3, h = bh & 7;
  int tid = threadIdx.x;
  int dg = tid >> 4, eg = tid & 15;
  float acc[4][4] = {{0.f}};
  for (int cch = 0; cch < 8; ++cch) {
    __syncthreads();
    for (int p = 0; p < 4; ++p) {
      int idx = p * 1024 + tid * 4;
      int cr = idx >> 6, ce = idx & 63;
      size_t base = ((size_t)(cch * 64 + cr)) * 512 + h * 64 + ce;
      fx4 v = {0.f, 0.f, 0.f, 0.f};
#pragma unroll
      for (int kk = 0; kk < 4; ++kk)
        v += *(const fx4*)&Ppart[(size_t)(kk * 8 + b) * 262144 + base];
      *(fx4*)&Ps[idx] = v;
      *(fx4*)&Ws[idx] = *(const fx4*)&w_qkv[(size_t)(cch * 64 + cr) * 1536 + h * 64 + ce];
    }
    __syncthreads();
    for (int cc = 0; cc < 64; ++cc) {
      fx4 wv = *(const fx4*)&Ws[cc * 64 + dg * 4];
      fx4 pv = *(const fx4*)&Ps[cc * 64 + eg * 4];
#pragma unroll
      for (int i = 0; i < 4; ++i)
#pragma unroll
        for (int j = 0; j < 4; ++j) acc[i][j] += wv[i] * pv[j];
    }
  }
  float tval = temp[h];
  __syncthreads();
#pragma unroll
  for (int i = 0; i < 4; ++i)
#pragma unroll
    for (int j = 0; j < 4; ++j) {
      int d = dg * 4 + i, e = eg * 4 + j;
      float ksum = u[b * 1024 + 512 + h * 64 + e] + 4096.0f * b_qkv[512 + h * 64 + e];
      Ss[d * 64 + e] = (acc[i][j] + b_qkv[h * 64 + d] * ksum) * tval;
    }
  __syncthreads();
  if (tid < 64) {
    float* row = &Ss[tid * 64];
    float mx = row[0];
    for (int e = 1; e < 64; ++e) mx = fmaxf(mx, row[e]);
    float sum = 0.f;
    for (int e = 0; e < 64; ++e) { float pv = __expf(row[e] - mx); row[e] = pv; sum += pv; }
    float inv = 1.f / sum;
    for (int e = 0; e < 64; ++e) row[e] *= inv;
  }
  __syncthreads();
  int jg = tid & 15, egr = tid >> 4;
  int j0 = jg * 8;
  for (int jc = 0; jc < 4; ++jc) {
    __syncthreads();
    for (int i = tid * 8; i < 8192; i += 2048) {
      int dd = i >> 7, c = i & 127;
      *(s16x8*)&wps[i] = *(const s16x8*)&wpb[(size_t)(h * 64 + dd) * 512 + jc * 128 + c];
    }
    __syncthreads();
    float a[4][8];
#pragma unroll
    for (int i = 0; i < 4; ++i)
#pragma unroll
      for (int j = 0; j < 8; ++j) a[i][j] = 0.f;
    for (int dd = 0; dd < 64; ++dd) {
      fx4 at = *(const fx4*)&Ss[dd * 64 + egr * 4];
      s16x8 wv = *(const s16x8*)&wps[dd * 128 + j0];
      float wf[8];
#pragma unroll
      for (int j = 0; j < 8; ++j) wf[j] = bf2f((unsigned short)wv[j]);
#pragma unroll
      for (int i = 0; i < 4; ++i)
#pragma unroll
        for (int j = 0; j < 8; ++j) a[i][j] += at[i] * wf[j];
    }
#pragma unroll
    for (int j = 0; j < 8; ++j) {
      float cb = 0.f;
#pragma unroll
      for (int i = 0; i < 4; ++i) {
        weffT[((size_t)b * 512 + jc * 128 + j0 + j) * 512 + h * 64 + egr * 4 + i] = f2bf(a[i][j]);
        cb += b_qkv[1024 + h * 64 + egr * 4 + i] * a[i][j];
      }
      atomicAdd(&bias_out[b * 512 + jc * 128 + j0 + j], cb);
    }
  }
}

// ---------------- host ----------------
extern "C" void kernel_launch(void* const* d_in, const int* in_sizes, int n_in,
                              void* d_out, int out_size, void* d_ws, size_t ws_size,
                              hipStream_t stream) {
  const float* x      = (const float*)d_in[0];
  const float* w_qkv  = (const float*)d_in[1];
  const float* b_qkv  = (const float*)d_in[2];
  const float* w_p    = (const float*)d_in[3];
  const float* b_p    = (const float*)d_in[4];
  const float* temp   = (const float*)d_in[5];
  float* out = (float*)d_out;
  char* ws = (char*)d_ws;

  unsigned short* xb     = (unsigned short*)(ws + 0);           // 32 MB
  unsigned short* xT     = (unsigned short*)(ws + 33554432);    // 32 MB (later: weffT/wcombT)
  unsigned short* kT     = (unsigned short*)(ws + 67108864);    // 32 MB
  float*          Ppart  = (float*)(ws + 100663296);            // 32 MB (early: s_part 1 MB)
  float*          s_part = (float*)(ws + 100663296);
  unsigned short* wkT    = (unsigned short*)(ws + 134217728);   // 512 KB
  unsigned short* wvb    = (unsigned short*)(ws + 134742016);   // 512 KB
  unsigned short* wpb    = (unsigned short*)(ws + 135266304);   // 512 KB
  float*          u      = (float*)(ws + 135790592);            // 32 KB
  float*          bias_o = (float*)(ws + 135823360);            // 16 KB
  unsigned short* weffT  = (unsigned short*)(ws + 33554432);    // 4 MB  (xT dead)
  unsigned short* wcombT = (unsigned short*)(ws + 37748736);    // 8 MB  (xT dead)

  hipMemsetAsync(u, 0, 32768, stream);
  cast_x_k<<<4096, 256, 0, stream>>>(x, xb, xT, s_part);
  wk_t_k<<<64, 256, 0, stream>>>(w_qkv, wkT);
  wvwp_k<<<256, 256, 0, stream>>>(w_qkv, w_p, wvb, wpb);
  ub_k<<<32, 256, 0, stream>>>(s_part, w_qkv, b_p, u, bias_o);
  gemm_k<0><<<1024, 256, 0, stream>>>(wkT, xb, b_qkv + 512, kT, nullptr);
  gemm_k<1><<<512, 256, 0, stream>>>(xT, kT, nullptr, nullptr, Ppart);
  scores_k<<<64, 256, 0, stream>>>(Ppart, w_qkv, b_qkv, u, temp, wpb, weffT, bias_o);
  gemm_k<2><<<128, 256, 0, stream>>>(weffT, wvb, nullptr, wcombT, nullptr);
  gemm_k<3><<<1024, 256, 0, stream>>>(xb, wcombT, bias_o, nullptr, out);
}

// Round 9
// 197.252 us; speedup vs baseline: 1.3788x; 1.3788x over previous
//
#include <hip/hip_runtime.h>

typedef __attribute__((ext_vector_type(8))) short s16x8;
typedef __attribute__((ext_vector_type(4))) short s16x4;
typedef __attribute__((ext_vector_type(4))) float fx4;

__device__ inline unsigned short f2bf(float f) {
  unsigned u = __float_as_uint(f);
  u += 0x7fffu + ((u >> 16) & 1u);
  return (unsigned short)(u >> 16);
}
__device__ inline float bf2f(unsigned short s) {
  return __uint_as_float(((unsigned)s) << 16);
}

#define GLDS16(gp, lp) \
  __builtin_amdgcn_global_load_lds((const __attribute__((address_space(1))) void*)(gp), \
                                   (__attribute__((address_space(3))) void*)(lp), 16, 0, 0)

// ---------------- cast_x: x f32 -> xb bf16 [b][n][c], xT bf16 [b][c][n],
// s_part[b][nt][c] = per-64-row column sums. grid 4096 = b*512 + nt*8 + ct.
__global__ __launch_bounds__(256) void cast_x_k(const float* __restrict__ x,
                                                unsigned short* __restrict__ xb,
                                                unsigned short* __restrict__ xT,
                                                float* __restrict__ s_part) {
  __shared__ unsigned short lt[64 * 66];  // [c][n] transposed tile
  __shared__ float red[64 * 4];
  int blk = blockIdx.x;
  int b = blk >> 9, r = blk & 511, nt = r >> 3, ct = r & 7;
  int n0 = nt * 64, c0 = ct * 64;
  int t = threadIdx.x;
  int rn = t >> 2, seg = (t & 3) * 16;
  const float* xp = x + ((size_t)b * 4096 + n0 + rn) * 512 + c0 + seg;
  fx4 v0 = *(const fx4*)&xp[0], v1 = *(const fx4*)&xp[4];
  fx4 v2 = *(const fx4*)&xp[8], v3 = *(const fx4*)&xp[12];
  unsigned short h[16];
  h[0]=f2bf(v0[0]); h[1]=f2bf(v0[1]); h[2]=f2bf(v0[2]); h[3]=f2bf(v0[3]);
  h[4]=f2bf(v1[0]); h[5]=f2bf(v1[1]); h[6]=f2bf(v1[2]); h[7]=f2bf(v1[3]);
  h[8]=f2bf(v2[0]); h[9]=f2bf(v2[1]); h[10]=f2bf(v2[2]); h[11]=f2bf(v2[3]);
  h[12]=f2bf(v3[0]); h[13]=f2bf(v3[1]); h[14]=f2bf(v3[2]); h[15]=f2bf(v3[3]);
  unsigned short* xbo = xb + ((size_t)b * 4096 + n0 + rn) * 512 + c0 + seg;
  *(s16x8*)&xbo[0] = *(s16x8*)&h[0];
  *(s16x8*)&xbo[8] = *(s16x8*)&h[8];
#pragma unroll
  for (int k = 0; k < 16; ++k) lt[(seg + k) * 66 + rn] = h[k];
  __syncthreads();
  {
    int c = t & 63, q = t >> 6;
    float p = 0.f;
#pragma unroll
    for (int i = 0; i < 16; ++i) p += bf2f(lt[c * 66 + q * 16 + i]);
    red[c * 4 + q] = p;
  }
  __syncthreads();
  if (t < 64) {
    float s = red[t * 4] + red[t * 4 + 1] + red[t * 4 + 2] + red[t * 4 + 3];
    s_part[((size_t)(b * 64 + nt)) * 512 + c0 + t] = s;
  }
  int c = t >> 2, nseg = (t & 3) * 16;
  unsigned short* xto = xT + ((size_t)b * 512 + c0 + c) * 4096 + n0 + nseg;
  *(s16x8*)&xto[0] = *(s16x8*)&lt[c * 66 + nseg];
  *(s16x8*)&xto[8] = *(s16x8*)&lt[c * 66 + nseg + 8];
}

// ---------------- wkT[e][c] = bf16(w_qkv[c][512+e]).  grid 64 = rt*8+ct
__global__ __launch_bounds__(256) void wk_t_k(const float* __restrict__ w,
                                              unsigned short* __restrict__ wkT) {
  __shared__ unsigned short lt[64 * 66];
  int blk = blockIdx.x;
  int rt = blk >> 3, ct = blk & 7;
  int t = threadIdx.x;
  int rn = t >> 2, seg = (t & 3) * 16;
  const float* wp = w + (size_t)(ct * 64 + rn) * 1536 + 512 + rt * 64 + seg;
#pragma unroll
  for (int k = 0; k < 16; ++k) lt[(seg + k) * 66 + rn] = f2bf(wp[k]);
  __syncthreads();
  int j = t >> 2, nseg = (t & 3) * 16;
  unsigned short* o = wkT + (size_t)(rt * 64 + j) * 512 + ct * 64 + nseg;
  *(s16x8*)&o[0] = *(s16x8*)&lt[j * 66 + nseg];
  *(s16x8*)&o[8] = *(s16x8*)&lt[j * 66 + nseg + 8];
}

// ---------------- wvb[c][e] = bf16(w_qkv[c][1024+e]); wpb = bf16(w_p). grid 256.
__global__ __launch_bounds__(256) void wvwp_k(const float* __restrict__ w,
                                              const float* __restrict__ wp,
                                              unsigned short* __restrict__ wvb,
                                              unsigned short* __restrict__ wpb) {
  int blk = blockIdx.x, t = threadIdx.x;
  if (blk < 128) {
    int o = blk * 2048 + t * 8;
    int c = o >> 9, e = o & 511;
    const float* src = w + (size_t)c * 1536 + 1024 + e;
    unsigned short h[8];
#pragma unroll
    for (int i = 0; i < 8; ++i) h[i] = f2bf(src[i]);
    *(s16x8*)&wvb[o] = *(s16x8*)&h[0];
  } else {
    int o = (blk - 128) * 2048 + t * 8;
    unsigned short h[8];
#pragma unroll
    for (int i = 0; i < 8; ++i) h[i] = f2bf(wp[o + i]);
    *(s16x8*)&wpb[o] = *(s16x8*)&h[0];
  }
}

// ---------------- ub: u[b][j] = dot(s_b, w_qkv[:, j]) for j<1024; init bias_out=b_p.
// grid 32 = b*4 + cq
__global__ __launch_bounds__(256) void ub_k(const float* __restrict__ s_part,
                                            const float* __restrict__ w,
                                            const float* __restrict__ b_p,
                                            float* __restrict__ u,
                                            float* __restrict__ bias_out) {
  __shared__ float sb[128];
  int b = blockIdx.x >> 2, cq = blockIdx.x & 3;
  int t = threadIdx.x;
  if (t < 128) {
    float a = 0.f;
    for (int nt = 0; nt < 64; ++nt)
      a += s_part[((size_t)(b * 64 + nt)) * 512 + cq * 128 + t];
    sb[t] = a;
  }
  __syncthreads();
  float ua0 = 0.f, ua1 = 0.f, ua2 = 0.f, ua3 = 0.f;
  for (int c = 0; c < 128; ++c) {
    float sc = sb[c];
    const float* wr = w + (size_t)(cq * 128 + c) * 1536;
    ua0 += sc * wr[t];
    ua1 += sc * wr[t + 256];
    ua2 += sc * wr[t + 512];
    ua3 += sc * wr[t + 768];
  }
  atomicAdd(&u[b * 1024 + t], ua0);
  atomicAdd(&u[b * 1024 + t + 256], ua1);
  atomicAdd(&u[b * 1024 + t + 512], ua2);
  atomicAdd(&u[b * 1024 + t + 768], ua3);
  if (cq == 0) {
    bias_out[b * 512 + t] = b_p[t];
    bias_out[b * 512 + 256 + t] = b_p[256 + t];
  }
}

// ---------------- GEMM: 128x128 tile, BK=32, 4 waves, 2-phase dbuf (R6-verified).
// MODE 0 (G):     A=BT=xT_b[512][4096]+ks*1024, K=1024 -> Gpart f32 [ks][b][c][c']
// MODE 1 (GWT):   A=wkT[512][512], BT=G16_b -> GWT[b][e][c] bf16
// MODE 2 (Wcomb): A=weffT_b, BT=wvb -> wcombT[b][j][c] bf16
// MODE 3 (final): A=xb_b[4096][512], BT=wcombT_b, bias/col -> out f32
template <int MODE>
__global__ __launch_bounds__(256, 4) void gemm_k(
    const unsigned short* __restrict__ A0, const unsigned short* __restrict__ B0,
    const float* __restrict__ bias, unsigned short* __restrict__ obf,
    float* __restrict__ of32) {
  constexpr int LD = (MODE == 0) ? 4096 : 512;
  constexpr int KSTEPS = (MODE == 0) ? 32 : 16;
  constexpr int NWG = (MODE == 0) ? 512 : (MODE == 3) ? 1024 : 128;
  __shared__ alignas(16) unsigned short As[2][128 * 32];
  __shared__ alignas(16) unsigned short Bs[2][128 * 32];
  int tid = threadIdx.x, wave = tid >> 6, lane = tid & 63;
  int l15 = lane & 15, l16 = lane >> 4;
  int wr = wave >> 1, wc = wave & 1;

  int bid = (blockIdx.x & 7) * (NWG >> 3) + (blockIdx.x >> 3);
  int b = 0, mt = 0, nt = 0, ks = 0;
  if (MODE == 0) { ks = bid >> 7; int r = bid & 127; b = r >> 4; mt = (r >> 2) & 3; nt = r & 3; }
  else if (MODE == 3) { b = bid >> 7; int r = bid & 127; mt = r >> 2; nt = r & 3; }
  else { b = bid >> 4; mt = (bid >> 2) & 3; nt = bid & 3; }

  const unsigned short* Ab;
  const unsigned short* Bb;
  if (MODE == 0) { Ab = A0 + ((size_t)b * 512 + mt * 128) * 4096 + ks * 1024;
                   Bb = A0 + ((size_t)b * 512 + nt * 128) * 4096 + ks * 1024; }
  else if (MODE == 1) { Ab = A0 + (size_t)mt * 128 * 512;
                        Bb = B0 + ((size_t)b * 512 + nt * 128) * 512; }
  else if (MODE == 2) { Ab = A0 + ((size_t)b * 512 + mt * 128) * 512;
                        Bb = B0 + (size_t)nt * 128 * 512; }
  else { Ab = A0 + ((size_t)b * 4096 + mt * 128) * 512;
         Bb = B0 + ((size_t)b * 512 + nt * 128) * 512; }

  fx4 acc[4][4];
#pragma unroll
  for (int i = 0; i < 4; ++i)
#pragma unroll
    for (int j = 0; j < 4; ++j) acc[i][j] = (fx4){0.f, 0.f, 0.f, 0.f};

  int smr = wave * 16 + (lane >> 2);
  int skk = (((lane & 3) ^ ((lane >> 3) & 3))) * 8;
  const unsigned short* agp = Ab + (size_t)smr * LD + skk;
  const unsigned short* bgp = Bb + (size_t)smr * LD + skk;
  int ldsoff = wave * 512;

#define STAGE(buf, kt_)                                          \
  do {                                                           \
    int k0_ = (kt_) * 32;                                        \
    GLDS16(agp + k0_, &As[buf][ldsoff]);                         \
    GLDS16(agp + (size_t)64 * LD + k0_, &As[buf][ldsoff + 2048]);\
    GLDS16(bgp + k0_, &Bs[buf][ldsoff]);                         \
    GLDS16(bgp + (size_t)64 * LD + k0_, &Bs[buf][ldsoff + 2048]);\
  } while (0)

  STAGE(0, 0);
  asm volatile("s_waitcnt vmcnt(0)" ::: "memory");
  __builtin_amdgcn_s_barrier();

  int g = (l15 >> 1) & 3;
  int pa = (l16 ^ g) << 3;

  for (int kt = 0; kt < KSTEPS; ++kt) {
    int cur = kt & 1;
    if (kt < KSTEPS - 1) STAGE(cur ^ 1, kt + 1);

    s16x8 af[4], bf[4];
#pragma unroll
    for (int mi = 0; mi < 4; ++mi)
      af[mi] = *(const s16x8*)&As[cur][(wr * 64 + mi * 16 + l15) * 32 + pa];
#pragma unroll
    for (int nj = 0; nj < 4; ++nj)
      bf[nj] = *(const s16x8*)&Bs[cur][(wc * 64 + nj * 16 + l15) * 32 + pa];
#pragma unroll
    for (int mi = 0; mi < 4; ++mi)
#pragma unroll
      for (int nj = 0; nj < 4; ++nj)
        acc[mi][nj] = __builtin_amdgcn_mfma_f32_16x16x32_bf16(af[mi], bf[nj], acc[mi][nj], 0, 0, 0);

    asm volatile("s_waitcnt vmcnt(0)" ::: "memory");
    __builtin_amdgcn_s_barrier();
  }
#undef STAGE

  int R0 = mt * 128 + wr * 64, C0 = nt * 128 + wc * 64;
#pragma unroll
  for (int mi = 0; mi < 4; ++mi)
#pragma unroll
    for (int nj = 0; nj < 4; ++nj) {
      int gc = C0 + nj * 16 + l15;
#pragma unroll
      for (int r = 0; r < 4; ++r) {
        int gr = R0 + mi * 16 + l16 * 4 + r;
        float val = acc[mi][nj][r];
        if (MODE == 0) {
          of32[(((size_t)(ks * 8 + b)) * 512 + gr) * 512 + gc] = val;
        } else if (MODE == 1) {
          obf[((size_t)(b * 512 + gr)) * 512 + gc] = f2bf(val);
        } else if (MODE == 2) {
          obf[((size_t)(b * 512 + gr)) * 512 + gc] = f2bf(val);
        } else {
          of32[((size_t)(b * 4096 + gr)) * 512 + gc] = val + bias[b * 512 + gc];
        }
      }
    }
}

// ---------------- gsum: G16[b][c][c'] = bf16(sum of 4 Gpart). grid 1024.
__global__ __launch_bounds__(256) void gsum_k(const float* __restrict__ Gpart,
                                              unsigned short* __restrict__ G16) {
  int i = (blockIdx.x * 256 + threadIdx.x) * 8;   // < 2097152
  fx4 a0 = {0.f,0.f,0.f,0.f}, a1 = {0.f,0.f,0.f,0.f};
#pragma unroll
  for (int p = 0; p < 4; ++p) {
    a0 += *(const fx4*)&Gpart[(size_t)p * 2097152 + i];
    a1 += *(const fx4*)&Gpart[(size_t)p * 2097152 + i + 4];
  }
  unsigned short h[8];
  h[0]=f2bf(a0[0]); h[1]=f2bf(a0[1]); h[2]=f2bf(a0[2]); h[3]=f2bf(a0[3]);
  h[4]=f2bf(a1[0]); h[5]=f2bf(a1[1]); h[6]=f2bf(a1[2]); h[7]=f2bf(a1[3]);
  *(s16x8*)&G16[i] = *(s16x8*)&h[0];
}

// ---------------- s_k: partial S over c-chunk. grid 512 = bh*8 + cch.
// sp[bh][cch][d][e] = sum_{c in chunk} Wq_f32[c, hd] * GWT[b][he][c]
__global__ __launch_bounds__(256) void s_k(const float* __restrict__ wq,
                                           const unsigned short* __restrict__ GWT,
                                           float* __restrict__ sp) {
  __shared__ alignas(16) float Ws[64 * 68];  // [c][d]
  __shared__ alignas(16) float Gs[64 * 68];  // [c][e]
  int bid = blockIdx.x;
  int bh = bid >> 3, cch = bid & 7;
  int b = bh >> 3, h = bh & 7;
  int t = threadIdx.x;
  int cr = t >> 2, sg = (t & 3) * 16;
  const float* wsrc = wq + (size_t)(cch * 64 + cr) * 1536 + h * 64 + sg;
#pragma unroll
  for (int kk = 0; kk < 16; ++kk) Ws[cr * 68 + sg + kk] = wsrc[kk];
  const unsigned short* gsrc = GWT + ((size_t)b * 512 + h * 64 + cr) * 512 + cch * 64 + sg;
#pragma unroll
  for (int kk = 0; kk < 16; ++kk) Gs[(sg + kk) * 68 + cr] = bf2f(gsrc[kk]);
  __syncthreads();
  int dg = t >> 4, eg = t & 15;
  float acc[4][4] = {{0.f}};
  for (int cc = 0; cc < 64; ++cc) {
    fx4 wv = *(const fx4*)&Ws[cc * 68 + dg * 4];
    fx4 pv = *(const fx4*)&Gs[cc * 68 + eg * 4];
#pragma unroll
    for (int i = 0; i < 4; ++i)
#pragma unroll
      for (int j = 0; j < 4; ++j) acc[i][j] += wv[i] * pv[j];
  }
  float* o = sp + (size_t)bid * 4096;
#pragma unroll
  for (int i = 0; i < 4; ++i)
#pragma unroll
    for (int j = 0; j < 4; ++j) o[(dg * 4 + i) * 64 + eg * 4 + j] = acc[i][j];
}

// ---------------- softmax + Weff. grid 256 = bh*4 + jblk (R6-proven structure).
__global__ __launch_bounds__(256) void softmax_weff_k(
    const float* __restrict__ sp, const unsigned short* __restrict__ wpb,
    const float* __restrict__ temp, const float* __restrict__ b_qkv,
    const float* __restrict__ u, unsigned short* __restrict__ weffT,
    float* __restrict__ bias_out) {
  __shared__ alignas(16) float S[64 * 64];
  __shared__ alignas(16) unsigned short wps[64 * 128];
  int bh = blockIdx.x >> 2, jblk = blockIdx.x & 3;
  int b = bh >> 3, h = bh & 7;
  int tid = threadIdx.x;
  float tval = temp[h];
  for (int i = tid * 4; i < 4096; i += 1024) {
    fx4 s = {0.f, 0.f, 0.f, 0.f};
    for (int seg = 0; seg < 8; ++seg)
      s += *(const fx4*)&sp[((size_t)(bh * 8 + seg)) * 4096 + i];
    int d = i >> 6, e0 = i & 63;
    float bq = b_qkv[h * 64 + d];
    float uq = u[b * 1024 + h * 64 + d];
#pragma unroll
    for (int jj = 0; jj < 4; ++jj) {
      int e = e0 + jj;
      float bk = b_qkv[512 + h * 64 + e];
      float ksum = u[b * 1024 + 512 + h * 64 + e] + 4096.0f * bk;
      s[jj] += bq * ksum + bk * uq;
    }
    s *= tval;
    *(fx4*)&S[i] = s;
  }
  for (int i = tid * 8; i < 8192; i += 2048) {
    int d = i >> 7, c = i & 127;
    *(s16x8*)&wps[i] = *(const s16x8*)&wpb[(size_t)(h * 64 + d) * 512 + jblk * 128 + c];
  }
  __syncthreads();
  if (tid < 64) {
    float* row = &S[tid * 64];
    float mx = row[0];
    for (int e = 1; e < 64; ++e) mx = fmaxf(mx, row[e]);
    float sum = 0.f;
    for (int e = 0; e < 64; ++e) { float p = __expf(row[e] - mx); row[e] = p; sum += p; }
    float inv = 1.f / sum;
    for (int e = 0; e < 64; ++e) row[e] *= inv;
  }
  __syncthreads();
  int jg = tid >> 4, eg = tid & 15;
  int j0 = jg * 8;
  float a[4][8];
#pragma unroll
  for (int i = 0; i < 4; ++i)
#pragma unroll
    for (int j = 0; j < 8; ++j) a[i][j] = 0.f;
  for (int d = 0; d < 64; ++d) {
    fx4 at = *(const fx4*)&S[d * 64 + eg * 4];
    s16x8 wv = *(const s16x8*)&wps[d * 128 + j0];
    float wf[8];
#pragma unroll
    for (int j = 0; j < 8; ++j) wf[j] = bf2f((unsigned short)wv[j]);
#pragma unroll
    for (int i = 0; i < 4; ++i)
#pragma unroll
      for (int j = 0; j < 8; ++j) a[i][j] += at[i] * wf[j];
  }
  int jglob = jblk * 128 + j0;
#pragma unroll
  for (int j = 0; j < 8; ++j) {
    float cb = 0.f;
#pragma unroll
    for (int i = 0; i < 4; ++i) {
      weffT[(((size_t)b * 512 + jglob + j) << 9) + h * 64 + eg * 4 + i] = f2bf(a[i][j]);
      cb += b_qkv[1024 + h * 64 + eg * 4 + i] * a[i][j];
    }
    atomicAdd(&bias_out[b * 512 + jglob + j], cb);
  }
}

// ---------------- host ----------------
extern "C" void kernel_launch(void* const* d_in, const int* in_sizes, int n_in,
                              void* d_out, int out_size, void* d_ws, size_t ws_size,
                              hipStream_t stream) {
  const float* x      = (const float*)d_in[0];
  const float* w_qkv  = (const float*)d_in[1];
  const float* b_qkv  = (const float*)d_in[2];
  const float* w_p    = (const float*)d_in[3];
  const float* b_p    = (const float*)d_in[4];
  const float* temp   = (const float*)d_in[5];
  float* out = (float*)d_out;
  char* ws = (char*)d_ws;

  unsigned short* xb     = (unsigned short*)(ws + 0);           // 32 MB
  unsigned short* xT     = (unsigned short*)(ws + 33554432);    // 32 MB (dead after G)
  float*          Gpart  = (float*)(ws + 67108864);             // 32 MB f32 [4][8][512][512]
  float*          s_part = (float*)(ws + 67108864);             // 1 MB (consumed before Gpart)
  unsigned short* G16    = (unsigned short*)(ws + 100663296);   // 4 MB
  unsigned short* GWT    = (unsigned short*)(ws + 104857600);   // 4 MB
  float*          sp     = (float*)(ws + 109051904);            // 8 MB
  unsigned short* wkT    = (unsigned short*)(ws + 117440512);   // 512 KB
  unsigned short* wvb    = (unsigned short*)(ws + 117964800);   // 512 KB
  unsigned short* wpb    = (unsigned short*)(ws + 118489088);   // 512 KB
  float*          u      = (float*)(ws + 119013376);            // 32 KB
  float*          bias_o = (float*)(ws + 119046144);            // 16 KB
  unsigned short* weffT  = (unsigned short*)(ws + 33554432);    // 4 MB (xT region)
  unsigned short* wcombT = (unsigned short*)(ws + 37748736);    // 4 MB (xT region)

  hipMemsetAsync(u, 0, 32768, stream);
  cast_x_k<<<4096, 256, 0, stream>>>(x, xb, xT, s_part);
  wk_t_k<<<64, 256, 0, stream>>>(w_qkv, wkT);
  wvwp_k<<<256, 256, 0, stream>>>(w_qkv, w_p, wvb, wpb);
  ub_k<<<32, 256, 0, stream>>>(s_part, w_qkv, b_p, u, bias_o);
  gemm_k<0><<<512, 256, 0, stream>>>(xT, nullptr, nullptr, nullptr, Gpart);
  gsum_k<<<1024, 256, 0, stream>>>(Gpart, G16);
  gemm_k<1><<<128, 256, 0, stream>>>(wkT, G16, nullptr, GWT, nullptr);
  s_k<<<512, 256, 0, stream>>>(w_qkv, GWT, sp);
  softmax_weff_k<<<256, 256, 0, stream>>>(sp, wpb, temp, b_qkv, u, weffT, bias_o);
  gemm_k<2><<<128, 256, 0, stream>>>(weffT, wvb, nullptr, wcombT, nullptr);
  gemm_k<3><<<1024, 256, 0, stream>>>(xb, wcombT, bias_o, nullptr, out);
}

// Round 10
// 163.517 us; speedup vs baseline: 1.6633x; 1.2063x over previous
//
#include <hip/hip_runtime.h>

typedef __attribute__((ext_vector_type(8))) short s16x8;
typedef __attribute__((ext_vector_type(4))) short s16x4;
typedef __attribute__((ext_vector_type(4))) float fx4;

__device__ inline unsigned short f2bf(float f) {
  unsigned u = __float_as_uint(f);
  u += 0x7fffu + ((u >> 16) & 1u);
  return (unsigned short)(u >> 16);
}
__device__ inline float bf2f(unsigned short s) {
  return __uint_as_float(((unsigned)s) << 16);
}

#define GLDS16(gp, lp) \
  __builtin_amdgcn_global_load_lds((const __attribute__((address_space(1))) void*)(gp), \
                                   (__attribute__((address_space(3))) void*)(lp), 16, 0, 0)

// ---------------- cast_x: x f32 -> xb bf16 [b][n][c], xT bf16 [b][c][n],
// s_part[b][nt][c] = per-64-row column sums. grid 4096 = b*512 + nt*8 + ct.
__global__ __launch_bounds__(256) void cast_x_k(const float* __restrict__ x,
                                                unsigned short* __restrict__ xb,
                                                unsigned short* __restrict__ xT,
                                                float* __restrict__ s_part) {
  __shared__ unsigned short lt[64 * 66];  // [c][n] transposed tile
  __shared__ float red[64 * 4];
  int blk = blockIdx.x;
  int b = blk >> 9, r = blk & 511, nt = r >> 3, ct = r & 7;
  int n0 = nt * 64, c0 = ct * 64;
  int t = threadIdx.x;
  int rn = t >> 2, seg = (t & 3) * 16;
  const float* xp = x + ((size_t)b * 4096 + n0 + rn) * 512 + c0 + seg;
  fx4 v0 = *(const fx4*)&xp[0], v1 = *(const fx4*)&xp[4];
  fx4 v2 = *(const fx4*)&xp[8], v3 = *(const fx4*)&xp[12];
  unsigned short h[16];
  h[0]=f2bf(v0[0]); h[1]=f2bf(v0[1]); h[2]=f2bf(v0[2]); h[3]=f2bf(v0[3]);
  h[4]=f2bf(v1[0]); h[5]=f2bf(v1[1]); h[6]=f2bf(v1[2]); h[7]=f2bf(v1[3]);
  h[8]=f2bf(v2[0]); h[9]=f2bf(v2[1]); h[10]=f2bf(v2[2]); h[11]=f2bf(v2[3]);
  h[12]=f2bf(v3[0]); h[13]=f2bf(v3[1]); h[14]=f2bf(v3[2]); h[15]=f2bf(v3[3]);
  unsigned short* xbo = xb + ((size_t)b * 4096 + n0 + rn) * 512 + c0 + seg;
  *(s16x8*)&xbo[0] = *(s16x8*)&h[0];
  *(s16x8*)&xbo[8] = *(s16x8*)&h[8];
#pragma unroll
  for (int k = 0; k < 16; ++k) lt[(seg + k) * 66 + rn] = h[k];
  __syncthreads();
  {
    int c = t & 63, q = t >> 6;
    float p = 0.f;
#pragma unroll
    for (int i = 0; i < 16; ++i) p += bf2f(lt[c * 66 + q * 16 + i]);
    red[c * 4 + q] = p;
  }
  __syncthreads();
  if (t < 64) {
    float s = red[t * 4] + red[t * 4 + 1] + red[t * 4 + 2] + red[t * 4 + 3];
    s_part[((size_t)(b * 64 + nt)) * 512 + c0 + t] = s;
  }
  int c = t >> 2, nseg = (t & 3) * 16;
  unsigned short* xto = xT + ((size_t)b * 512 + c0 + c) * 4096 + n0 + nseg;
  *(s16x8*)&xto[0] = *(s16x8*)&lt[c * 66 + nseg];
  *(s16x8*)&xto[8] = *(s16x8*)&lt[c * 66 + nseg + 8];
}

// ---------------- wkT[e][c] = bf16(w_qkv[c][512+e]).  grid 64 = rt*8+ct
__global__ __launch_bounds__(256) void wk_t_k(const float* __restrict__ w,
                                              unsigned short* __restrict__ wkT) {
  __shared__ unsigned short lt[64 * 66];
  int blk = blockIdx.x;
  int rt = blk >> 3, ct = blk & 7;
  int t = threadIdx.x;
  int rn = t >> 2, seg = (t & 3) * 16;
  const float* wp = w + (size_t)(ct * 64 + rn) * 1536 + 512 + rt * 64 + seg;
#pragma unroll
  for (int k = 0; k < 16; ++k) lt[(seg + k) * 66 + rn] = f2bf(wp[k]);
  __syncthreads();
  int j = t >> 2, nseg = (t & 3) * 16;
  unsigned short* o = wkT + (size_t)(rt * 64 + j) * 512 + ct * 64 + nseg;
  *(s16x8*)&o[0] = *(s16x8*)&lt[j * 66 + nseg];
  *(s16x8*)&o[8] = *(s16x8*)&lt[j * 66 + nseg + 8];
}

// ---------------- wvb[c][e] = bf16(w_qkv[c][1024+e]); wpb = bf16(w_p). grid 256.
__global__ __launch_bounds__(256) void wvwp_k(const float* __restrict__ w,
                                              const float* __restrict__ wp,
                                              unsigned short* __restrict__ wvb,
                                              unsigned short* __restrict__ wpb) {
  int blk = blockIdx.x, t = threadIdx.x;
  if (blk < 128) {
    int o = blk * 2048 + t * 8;
    int c = o >> 9, e = o & 511;
    const float* src = w + (size_t)c * 1536 + 1024 + e;
    unsigned short h[8];
#pragma unroll
    for (int i = 0; i < 8; ++i) h[i] = f2bf(src[i]);
    *(s16x8*)&wvb[o] = *(s16x8*)&h[0];
  } else {
    int o = (blk - 128) * 2048 + t * 8;
    unsigned short h[8];
#pragma unroll
    for (int i = 0; i < 8; ++i) h[i] = f2bf(wp[o + i]);
    *(s16x8*)&wpb[o] = *(s16x8*)&h[0];
  }
}

// ---------------- ub: u[b][j] = dot(s_b, w_qkv[:, j]) for j<1024. grid 32.
__global__ __launch_bounds__(256) void ub_k(const float* __restrict__ s_part,
                                            const float* __restrict__ w,
                                            float* __restrict__ u) {
  __shared__ float sb[128];
  int b = blockIdx.x >> 2, cq = blockIdx.x & 3;
  int t = threadIdx.x;
  if (t < 128) {
    float a = 0.f;
    for (int nt = 0; nt < 64; ++nt)
      a += s_part[((size_t)(b * 64 + nt)) * 512 + cq * 128 + t];
    sb[t] = a;
  }
  __syncthreads();
  float ua0 = 0.f, ua1 = 0.f, ua2 = 0.f, ua3 = 0.f;
  for (int c = 0; c < 128; ++c) {
    float sc = sb[c];
    const float* wr = w + (size_t)(cq * 128 + c) * 1536;
    ua0 += sc * wr[t];
    ua1 += sc * wr[t + 256];
    ua2 += sc * wr[t + 512];
    ua3 += sc * wr[t + 768];
  }
  atomicAdd(&u[b * 1024 + t], ua0);
  atomicAdd(&u[b * 1024 + t + 256], ua1);
  atomicAdd(&u[b * 1024 + t + 512], ua2);
  atomicAdd(&u[b * 1024 + t + 768], ua3);
}

// ---------------- GEMM: 128x128 tile, BK=32, 4 waves, 2-phase dbuf (R6-verified).
// MODE 0 (G):     A=BT=xT_b[512][4096]+ks*1024, K=1024 -> Gpart f32 [ks][b][c][c']
// MODE 1 (GWT):   A=wkT[512][512], BT=G16_b -> GWT[b][e][c] bf16
// MODE 2 (Wcomb): A=weffT_b, BT=wvb -> wcombT[b][j][c] bf16
// MODE 3 (final): A=xb_b[4096][512], BT=wcombT_b, bias/col -> out f32
template <int MODE>
__global__ __launch_bounds__(256, 4) void gemm_k(
    const unsigned short* __restrict__ A0, const unsigned short* __restrict__ B0,
    const float* __restrict__ bias, unsigned short* __restrict__ obf,
    float* __restrict__ of32) {
  constexpr int LD = (MODE == 0) ? 4096 : 512;
  constexpr int KSTEPS = (MODE == 0) ? 32 : 16;
  constexpr int NWG = (MODE == 0) ? 512 : (MODE == 3) ? 1024 : 128;
  __shared__ alignas(16) unsigned short As[2][128 * 32];
  __shared__ alignas(16) unsigned short Bs[2][128 * 32];
  int tid = threadIdx.x, wave = tid >> 6, lane = tid & 63;
  int l15 = lane & 15, l16 = lane >> 4;
  int wr = wave >> 1, wc = wave & 1;

  int bid = (blockIdx.x & 7) * (NWG >> 3) + (blockIdx.x >> 3);
  int b = 0, mt = 0, nt = 0, ks = 0;
  if (MODE == 0) { ks = bid >> 7; int r = bid & 127; b = r >> 4; mt = (r >> 2) & 3; nt = r & 3; }
  else if (MODE == 3) { b = bid >> 7; int r = bid & 127; mt = r >> 2; nt = r & 3; }
  else { b = bid >> 4; mt = (bid >> 2) & 3; nt = bid & 3; }

  const unsigned short* Ab;
  const unsigned short* Bb;
  if (MODE == 0) { Ab = A0 + ((size_t)b * 512 + mt * 128) * 4096 + ks * 1024;
                   Bb = A0 + ((size_t)b * 512 + nt * 128) * 4096 + ks * 1024; }
  else if (MODE == 1) { Ab = A0 + (size_t)mt * 128 * 512;
                        Bb = B0 + ((size_t)b * 512 + nt * 128) * 512; }
  else if (MODE == 2) { Ab = A0 + ((size_t)b * 512 + mt * 128) * 512;
                        Bb = B0 + (size_t)nt * 128 * 512; }
  else { Ab = A0 + ((size_t)b * 4096 + mt * 128) * 512;
         Bb = B0 + ((size_t)b * 512 + nt * 128) * 512; }

  fx4 acc[4][4];
#pragma unroll
  for (int i = 0; i < 4; ++i)
#pragma unroll
    for (int j = 0; j < 4; ++j) acc[i][j] = (fx4){0.f, 0.f, 0.f, 0.f};

  int smr = wave * 16 + (lane >> 2);
  int skk = (((lane & 3) ^ ((lane >> 3) & 3))) * 8;
  const unsigned short* agp = Ab + (size_t)smr * LD + skk;
  const unsigned short* bgp = Bb + (size_t)smr * LD + skk;
  int ldsoff = wave * 512;

#define STAGE(buf, kt_)                                          \
  do {                                                           \
    int k0_ = (kt_) * 32;                                        \
    GLDS16(agp + k0_, &As[buf][ldsoff]);                         \
    GLDS16(agp + (size_t)64 * LD + k0_, &As[buf][ldsoff + 2048]);\
    GLDS16(bgp + k0_, &Bs[buf][ldsoff]);                         \
    GLDS16(bgp + (size_t)64 * LD + k0_, &Bs[buf][ldsoff + 2048]);\
  } while (0)

  STAGE(0, 0);
  asm volatile("s_waitcnt vmcnt(0)" ::: "memory");
  __builtin_amdgcn_s_barrier();

  int g = (l15 >> 1) & 3;
  int pa = (l16 ^ g) << 3;

  for (int kt = 0; kt < KSTEPS; ++kt) {
    int cur = kt & 1;
    if (kt < KSTEPS - 1) STAGE(cur ^ 1, kt + 1);

    s16x8 af[4], bf[4];
#pragma unroll
    for (int mi = 0; mi < 4; ++mi)
      af[mi] = *(const s16x8*)&As[cur][(wr * 64 + mi * 16 + l15) * 32 + pa];
#pragma unroll
    for (int nj = 0; nj < 4; ++nj)
      bf[nj] = *(const s16x8*)&Bs[cur][(wc * 64 + nj * 16 + l15) * 32 + pa];
#pragma unroll
    for (int mi = 0; mi < 4; ++mi)
#pragma unroll
      for (int nj = 0; nj < 4; ++nj)
        acc[mi][nj] = __builtin_amdgcn_mfma_f32_16x16x32_bf16(af[mi], bf[nj], acc[mi][nj], 0, 0, 0);

    asm volatile("s_waitcnt vmcnt(0)" ::: "memory");
    __builtin_amdgcn_s_barrier();
  }
#undef STAGE

  int R0 = mt * 128 + wr * 64, C0 = nt * 128 + wc * 64;
#pragma unroll
  for (int mi = 0; mi < 4; ++mi)
#pragma unroll
    for (int nj = 0; nj < 4; ++nj) {
      int gc = C0 + nj * 16 + l15;
#pragma unroll
      for (int r = 0; r < 4; ++r) {
        int gr = R0 + mi * 16 + l16 * 4 + r;
        float val = acc[mi][nj][r];
        if (MODE == 0) {
          of32[(((size_t)(ks * 8 + b)) * 512 + gr) * 512 + gc] = val;
        } else if (MODE == 1) {
          obf[((size_t)(b * 512 + gr)) * 512 + gc] = f2bf(val);
        } else if (MODE == 2) {
          obf[((size_t)(b * 512 + gr)) * 512 + gc] = f2bf(val);
        } else {
          of32[((size_t)(b * 4096 + gr)) * 512 + gc] = val + bias[b * 512 + gc];
        }
      }
    }
}

// ---------------- gsum: G16[b][c][c'] = bf16(sum of 4 Gpart). grid 1024.
__global__ __launch_bounds__(256) void gsum_k(const float* __restrict__ Gpart,
                                              unsigned short* __restrict__ G16) {
  int i = (blockIdx.x * 256 + threadIdx.x) * 8;   // < 2097152
  fx4 a0 = {0.f,0.f,0.f,0.f}, a1 = {0.f,0.f,0.f,0.f};
#pragma unroll
  for (int p = 0; p < 4; ++p) {
    a0 += *(const fx4*)&Gpart[(size_t)p * 2097152 + i];
    a1 += *(const fx4*)&Gpart[(size_t)p * 2097152 + i + 4];
  }
  unsigned short h[8];
  h[0]=f2bf(a0[0]); h[1]=f2bf(a0[1]); h[2]=f2bf(a0[2]); h[3]=f2bf(a0[3]);
  h[4]=f2bf(a1[0]); h[5]=f2bf(a1[1]); h[6]=f2bf(a1[2]); h[7]=f2bf(a1[3]);
  *(s16x8*)&G16[i] = *(s16x8*)&h[0];
}

// ---------------- s_k: partial S over c-chunk. grid 512 = bh*8 + cch.
// sp[bh][cch][d][e] = sum_{c in chunk} Wq_f32[c, hd] * GWT[b][he][c]
__global__ __launch_bounds__(256) void s_k(const float* __restrict__ wq,
                                           const unsigned short* __restrict__ GWT,
                                           float* __restrict__ sp) {
  __shared__ alignas(16) float Ws[64 * 68];  // [c][d]
  __shared__ alignas(16) float Gs[64 * 68];  // [c][e]
  int bid = blockIdx.x;
  int bh = bid >> 3, cch = bid & 7;
  int b = bh >> 3, h = bh & 7;
  int t = threadIdx.x;
  int cr = t >> 2, sg = (t & 3) * 16;
  const float* wsrc = wq + (size_t)(cch * 64 + cr) * 1536 + h * 64 + sg;
#pragma unroll
  for (int kk = 0; kk < 16; ++kk) Ws[cr * 68 + sg + kk] = wsrc[kk];
  const unsigned short* gsrc = GWT + ((size_t)b * 512 + h * 64 + cr) * 512 + cch * 64 + sg;
#pragma unroll
  for (int kk = 0; kk < 16; ++kk) Gs[(sg + kk) * 68 + cr] = bf2f(gsrc[kk]);
  __syncthreads();
  int dg = t >> 4, eg = t & 15;
  float acc[4][4] = {{0.f}};
  for (int cc = 0; cc < 64; ++cc) {
    fx4 wv = *(const fx4*)&Ws[cc * 68 + dg * 4];
    fx4 pv = *(const fx4*)&Gs[cc * 68 + eg * 4];
#pragma unroll
    for (int i = 0; i < 4; ++i)
#pragma unroll
      for (int j = 0; j < 4; ++j) acc[i][j] += wv[i] * pv[j];
  }
  float* o = sp + (size_t)bid * 4096;
#pragma unroll
  for (int i = 0; i < 4; ++i)
#pragma unroll
    for (int j = 0; j < 4; ++j) o[(dg * 4 + i) * 64 + eg * 4 + j] = acc[i][j];
}

// ---------------- softmax + Weff. grid 256 = bh*4 + jblk. NO atomics; 8B stores.
__global__ __launch_bounds__(256) void softmax_weff_k(
    const float* __restrict__ sp, const unsigned short* __restrict__ wpb,
    const float* __restrict__ temp, const float* __restrict__ b_qkv,
    const float* __restrict__ u, unsigned short* __restrict__ weffT) {
  __shared__ alignas(16) float S[64 * 64];
  __shared__ alignas(16) unsigned short wps[64 * 128];
  int bh = blockIdx.x >> 2, jblk = blockIdx.x & 3;
  int b = bh >> 3, h = bh & 7;
  int tid = threadIdx.x;
  float tval = temp[h];
  for (int i = tid * 4; i < 4096; i += 1024) {
    fx4 s = {0.f, 0.f, 0.f, 0.f};
    for (int seg = 0; seg < 8; ++seg)
      s += *(const fx4*)&sp[((size_t)(bh * 8 + seg)) * 4096 + i];
    int d = i >> 6, e0 = i & 63;
    float bq = b_qkv[h * 64 + d];
    float uq = u[b * 1024 + h * 64 + d];
#pragma unroll
    for (int jj = 0; jj < 4; ++jj) {
      int e = e0 + jj;
      float bk = b_qkv[512 + h * 64 + e];
      float ksum = u[b * 1024 + 512 + h * 64 + e] + 4096.0f * bk;
      s[jj] += bq * ksum + bk * uq;
    }
    s *= tval;
    *(fx4*)&S[i] = s;
  }
  for (int i = tid * 8; i < 8192; i += 2048) {
    int d = i >> 7, c = i & 127;
    *(s16x8*)&wps[i] = *(const s16x8*)&wpb[(size_t)(h * 64 + d) * 512 + jblk * 128 + c];
  }
  __syncthreads();
  if (tid < 64) {
    float* row = &S[tid * 64];
    float mx = row[0];
    for (int e = 1; e < 64; ++e) mx = fmaxf(mx, row[e]);
    float sum = 0.f;
    for (int e = 0; e < 64; ++e) { float p = __expf(row[e] - mx); row[e] = p; sum += p; }
    float inv = 1.f / sum;
    for (int e = 0; e < 64; ++e) row[e] *= inv;
  }
  __syncthreads();
  int jg = tid >> 4, eg = tid & 15;
  int j0 = jg * 8;
  float a[4][8];
#pragma unroll
  for (int i = 0; i < 4; ++i)
#pragma unroll
    for (int j = 0; j < 8; ++j) a[i][j] = 0.f;
  for (int d = 0; d < 64; ++d) {
    fx4 at = *(const fx4*)&S[d * 64 + eg * 4];
    s16x8 wv = *(const s16x8*)&wps[d * 128 + j0];
    float wf[8];
#pragma unroll
    for (int j = 0; j < 8; ++j) wf[j] = bf2f((unsigned short)wv[j]);
#pragma unroll
    for (int i = 0; i < 4; ++i)
#pragma unroll
      for (int j = 0; j < 8; ++j) a[i][j] += at[i] * wf[j];
  }
  int jglob = jblk * 128 + j0;
#pragma unroll
  for (int j = 0; j < 8; ++j) {
    unsigned short h4[4];
#pragma unroll
    for (int i = 0; i < 4; ++i) h4[i] = f2bf(a[i][j]);
    *(s16x4*)&weffT[(((size_t)b * 512 + jglob + j) << 9) + h * 64 + eg * 4] = *(s16x4*)&h4[0];
  }
}

// ---------------- bias2: bias_out[b][j] = b_p[j] + sum_e bv[e]*WeffT[b][j][e]. grid 8.
__global__ __launch_bounds__(256) void bias2_k(const unsigned short* __restrict__ weffT,
                                               const float* __restrict__ b_qkv,
                                               const float* __restrict__ b_p,
                                               float* __restrict__ bias_out) {
  __shared__ float bv[512];
  int b = blockIdx.x;
  int t = threadIdx.x;
  bv[t] = b_qkv[1024 + t];
  bv[t + 256] = b_qkv[1280 + t];
  __syncthreads();
#pragma unroll
  for (int jj = 0; jj < 2; ++jj) {
    int j = jj * 256 + t;
    const unsigned short* wrow = &weffT[((size_t)(b * 512 + j)) << 9];
    float s = 0.f;
    for (int e = 0; e < 512; e += 8) {
      s16x8 v = *(const s16x8*)&wrow[e];
#pragma unroll
      for (int q = 0; q < 8; ++q) s += bv[e + q] * bf2f((unsigned short)v[q]);
    }
    bias_out[b * 512 + j] = b_p[j] + s;
  }
}

// ---------------- host ----------------
extern "C" void kernel_launch(void* const* d_in, const int* in_sizes, int n_in,
                              void* d_out, int out_size, void* d_ws, size_t ws_size,
                              hipStream_t stream) {
  const float* x      = (const float*)d_in[0];
  const float* w_qkv  = (const float*)d_in[1];
  const float* b_qkv  = (const float*)d_in[2];
  const float* w_p    = (const float*)d_in[3];
  const float* b_p    = (const float*)d_in[4];
  const float* temp   = (const float*)d_in[5];
  float* out = (float*)d_out;
  char* ws = (char*)d_ws;

  unsigned short* xb     = (unsigned short*)(ws + 0);           // 32 MB
  unsigned short* xT     = (unsigned short*)(ws + 33554432);    // 32 MB (dead after G)
  float*          Gpart  = (float*)(ws + 67108864);             // 32 MB f32 [4][8][512][512]
  float*          s_part = (float*)(ws + 67108864);             // 1 MB (consumed before Gpart)
  unsigned short* G16    = (unsigned short*)(ws + 100663296);   // 4 MB
  unsigned short* GWT    = (unsigned short*)(ws + 104857600);   // 4 MB
  float*          sp     = (float*)(ws + 109051904);            // 8 MB
  unsigned short* wkT    = (unsigned short*)(ws + 117440512);   // 512 KB
  unsigned short* wvb    = (unsigned short*)(ws + 117964800);   // 512 KB
  unsigned short* wpb    = (unsigned short*)(ws + 118489088);   // 512 KB
  float*          u      = (float*)(ws + 119013376);            // 32 KB
  float*          bias_o = (float*)(ws + 119046144);            // 16 KB
  unsigned short* weffT  = (unsigned short*)(ws + 33554432);    // 4 MB (xT region)
  unsigned short* wcombT = (unsigned short*)(ws + 37748736);    // 4 MB (xT region)

  hipMemsetAsync(u, 0, 32768, stream);
  cast_x_k<<<4096, 256, 0, stream>>>(x, xb, xT, s_part);
  wk_t_k<<<64, 256, 0, stream>>>(w_qkv, wkT);
  wvwp_k<<<256, 256, 0, stream>>>(w_qkv, w_p, wvb, wpb);
  ub_k<<<32, 256, 0, stream>>>(s_part, w_qkv, u);
  gemm_k<0><<<512, 256, 0, stream>>>(xT, nullptr, nullptr, nullptr, Gpart);
  gsum_k<<<1024, 256, 0, stream>>>(Gpart, G16);
  gemm_k<1><<<128, 256, 0, stream>>>(wkT, G16, nullptr, GWT, nullptr);
  s_k<<<512, 256, 0, stream>>>(w_qkv, GWT, sp);
  softmax_weff_k<<<256, 256, 0, stream>>>(sp, wpb, temp, b_qkv, u, weffT);
  bias2_k<<<8, 256, 0, stream>>>(weffT, b_qkv, b_p, bias_o);
  gemm_k<2><<<128, 256, 0, stream>>>(weffT, wvb, nullptr, wcombT, nullptr);
  gemm_k<3><<<1024, 256, 0, stream>>>(xb, wcombT, bias_o, nullptr, out);
}